// Round 3
// baseline (161.300 us; speedup 1.0000x reference)
//
#include <hip/hip_runtime.h>

// GATv1-style single-head attention, N=8192, F_in=128, F_out=64, alpha=0.2.
// exp(leakyrelu(s_i + d_j)) is separable per branch; the branch predicate is
// monotone in d_j. Partition j into 8 sorted runs of 1024 (per-block LDS bitonic),
// permute Wh rows into sorted order (coalesced), precompute e^d / e^{0.2d}, and
// build prefix tables sampled every 8 sorted elements. Each output row does 8
// wave-uniform binary searches + table lookups + <=7 coalesced residual terms
// per run. O(N^2 F) -> O(N(logN + F)). 3 dispatches total.

typedef unsigned long long ull;

constexpr int N_ROWS = 8192;
constexpr int F_IN   = 128;
constexpr int F_OUT  = 64;
#define LRELU_ALPHA 0.2f

constexpr int NRUN   = 8;      // independent sorted runs
constexpr int RUNLEN = 1024;   // elements per run (= sort block threads)
constexpr int SBLK   = 8;      // prefix-table sampling granularity
constexpr int NGRP   = RUNLEN / SBLK;   // 128 groups per run; tables have NGRP+1 entries

// workspace layout in floats (total ~1.23M floats = 4.9 MB; ws is 256 MiB)
constexpr int WS_WH   = 0;                                  // Wh row-major [j][c]
constexpr int WS_ESRC = WS_WH + N_ROWS * F_OUT;             // e_src[i]
constexpr int WS_KEYS = WS_ESRC + N_ROWS;                   // 8192 ull
constexpr int WS_WHS  = WS_KEYS + 2 * N_ROWS;               // Wh permuted to sorted order
constexpr int WS_E1   = WS_WHS + N_ROWS * F_OUT;            // e^{d_u} sorted order
constexpr int WS_E2   = WS_E1 + N_ROWS;                     // e^{0.2 d_u}
constexpr int WS_DS   = WS_E2 + N_ROWS;                     // d_u sorted order (f32)
constexpr int WS_P1   = WS_DS + N_ROWS;                     // [run][b][c], b in [0,128]
constexpr int WS_P2   = WS_P1 + NRUN * (NGRP + 1) * F_OUT;
constexpr int WS_D1   = WS_P2 + NRUN * (NGRP + 1) * F_OUT;  // [run][b]
constexpr int WS_D2   = WS_D1 + NRUN * (NGRP + 1);
static_assert((WS_KEYS % 2) == 0, "keys 8B-aligned");

// monotone float<->uint mapping (ascending uint order == ascending float order)
__device__ __forceinline__ unsigned mono_enc(float f) {
  unsigned u = __float_as_uint(f);
  return u ^ ((u & 0x80000000u) ? 0xFFFFFFFFu : 0x80000000u);
}
__device__ __forceinline__ float mono_dec(unsigned e) {
  unsigned u = e ^ ((e & 0x80000000u) ? 0x80000000u : 0xFFFFFFFFu);
  return __uint_as_float(u);
}

// ---------------- K1: Wh = h @ W ; e_src = Wh@a1 ; keys = (enc(Wh@a2), j) ----------------
// grid 512 x 256 threads. 16 rows/block, wave handles 4 rows, lane = output col.
__global__ __launch_bounds__(256) void k1_wh(const float* __restrict__ h,
                                             const float* __restrict__ W,
                                             const float* __restrict__ a,
                                             float* __restrict__ ws) {
  __shared__ float hlds[16 * F_IN];    // 8 KB
  __shared__ float alds[2 * F_OUT];
  const int t = threadIdx.x;
  const int row0 = blockIdx.x * 16;

  const float4* hsrc = (const float4*)(h + (long)row0 * F_IN);
  float4* hd = (float4*)hlds;
  hd[t]       = hsrc[t];
  hd[t + 256] = hsrc[t + 256];
  if (t < 2 * F_OUT) alds[t] = a[t];
  __syncthreads();

  const int wave = t >> 6, lane = t & 63;
  const float* hp = hlds + (wave * 4) * F_IN;
  float acc0 = 0.f, acc1 = 0.f, acc2 = 0.f, acc3 = 0.f;

  #pragma unroll 4
  for (int k4 = 0; k4 < F_IN; k4 += 4) {
    float4 h0 = *(const float4*)(hp + k4);
    float4 h1 = *(const float4*)(hp + F_IN + k4);
    float4 h2 = *(const float4*)(hp + 2 * F_IN + k4);
    float4 h3 = *(const float4*)(hp + 3 * F_IN + k4);
    float w0 = W[(k4 + 0) * F_OUT + lane];
    float w1 = W[(k4 + 1) * F_OUT + lane];
    float w2 = W[(k4 + 2) * F_OUT + lane];
    float w3 = W[(k4 + 3) * F_OUT + lane];
    acc0 = fmaf(h0.x, w0, acc0); acc0 = fmaf(h0.y, w1, acc0);
    acc0 = fmaf(h0.z, w2, acc0); acc0 = fmaf(h0.w, w3, acc0);
    acc1 = fmaf(h1.x, w0, acc1); acc1 = fmaf(h1.y, w1, acc1);
    acc1 = fmaf(h1.z, w2, acc1); acc1 = fmaf(h1.w, w3, acc1);
    acc2 = fmaf(h2.x, w0, acc2); acc2 = fmaf(h2.y, w1, acc2);
    acc2 = fmaf(h2.z, w2, acc2); acc2 = fmaf(h2.w, w3, acc2);
    acc3 = fmaf(h3.x, w0, acc3); acc3 = fmaf(h3.y, w1, acc3);
    acc3 = fmaf(h3.z, w2, acc3); acc3 = fmaf(h3.w, w3, acc3);
  }

  const int grow = row0 + wave * 4;
  float* Wh = ws + WS_WH;
  Wh[(grow + 0) * F_OUT + lane] = acc0;
  Wh[(grow + 1) * F_OUT + lane] = acc1;
  Wh[(grow + 2) * F_OUT + lane] = acc2;
  Wh[(grow + 3) * F_OUT + lane] = acc3;

  const float a1 = alds[lane], a2 = alds[F_OUT + lane];
  float s0 = acc0 * a1, s1 = acc1 * a1, s2 = acc2 * a1, s3 = acc3 * a1;
  float d0 = acc0 * a2, d1 = acc1 * a2, d2 = acc2 * a2, d3 = acc3 * a2;
  #pragma unroll
  for (int off = 32; off; off >>= 1) {
    s0 += __shfl_down(s0, off); s1 += __shfl_down(s1, off);
    s2 += __shfl_down(s2, off); s3 += __shfl_down(s3, off);
    d0 += __shfl_down(d0, off); d1 += __shfl_down(d1, off);
    d2 += __shfl_down(d2, off); d3 += __shfl_down(d3, off);
  }
  if (lane == 0) {
    ws[WS_ESRC + grow + 0] = s0; ws[WS_ESRC + grow + 1] = s1;
    ws[WS_ESRC + grow + 2] = s2; ws[WS_ESRC + grow + 3] = s3;
    ull* keys = (ull*)(ws + WS_KEYS);
    keys[grow + 0] = ((ull)mono_enc(d0) << 32) | (unsigned)(grow + 0);
    keys[grow + 1] = ((ull)mono_enc(d1) << 32) | (unsigned)(grow + 1);
    keys[grow + 2] = ((ull)mono_enc(d2) << 32) | (unsigned)(grow + 2);
    keys[grow + 3] = ((ull)mono_enc(d3) << 32) | (unsigned)(grow + 3);
  }
}

// ---------------- K23: per-run LDS bitonic sort + permute + exp + sampled prefix scan -----
// grid NRUN x 1024 threads. Block r owns run r (sorted indices [1024r, 1024r+1024)).
// Phase 1: bitonic sort of 1024 keys in LDS (one element per thread; proven pattern).
// Phase 2: wave w owns sorted-local elements [64w, 64w+64) = 8 groups of 8:
//   gathers Wh rows coalescently (lane=column), writes WhS/E1/E2/DS, accumulates
//   per-lane column sums with register-recorded group prefixes.
// Phase 3: 16 wave-totals combined via LDS -> exclusive offsets -> coalesced table writes.
__global__ __launch_bounds__(1024) void k23_sort_scan(float* __restrict__ ws) {
  __shared__ ull lk[RUNLEN];          // 8 KB
  __shared__ float wt1[16][64], wt2[16][64];   // wave totals per column, 8 KB
  __shared__ float wtd1[16], wtd2[16];

  const int t = threadIdx.x;
  const int run = blockIdx.x;
  const int rbase = run * RUNLEN;
  const ull* keys = (const ull*)(ws + WS_KEYS);

  lk[t] = keys[rbase + t];
  __syncthreads();
  for (int k = 2; k <= RUNLEN; k <<= 1) {
    for (int j = k >> 1; j > 0; j >>= 1) {
      int p = t ^ j;
      if (p > t) {
        ull x = lk[t], y = lk[p];
        bool asc = ((t & k) == 0);
        if ((x > y) == asc) { lk[t] = y; lk[p] = x; }
      }
      __syncthreads();
    }
  }

  const int wv = t >> 6, lane = t & 63;
  const float* Wh = ws + WS_WH;
  float* WhS = ws + WS_WHS;

  float S1 = 0.f, S2 = 0.f;       // per-lane (column) running sums
  float sd1 = 0.f, sd2 = 0.f;     // denominator running sums (lane-replicated)
  float pre1[SBLK], pre2[SBLK], pd1[SBLK], pd2[SBLK];

  #pragma unroll
  for (int k = 0; k < SBLK; ++k) {          // 8 groups per wave
    pre1[k] = S1; pre2[k] = S2; pd1[k] = sd1; pd2[k] = sd2;
    #pragma unroll
    for (int o = 0; o < SBLK; ++o) {
      const int ul = wv * 64 + k * 8 + o;   // sorted-local index
      const ull key = lk[ul];
      const float d = mono_dec((unsigned)(key >> 32));
      const int j = (int)(key & 0xFFFFFFFFu);
      const float e1 = __expf(d), e2 = __expf(LRELU_ALPHA * d);
      const float v = Wh[j * F_OUT + lane];   // coalesced 256B row gather
      const int u = rbase + ul;
      WhS[u * F_OUT + lane] = v;              // coalesced row store
      if (lane == 0) {
        ws[WS_DS + u] = d; ws[WS_E1 + u] = e1; ws[WS_E2 + u] = e2;
      }
      S1 = fmaf(e1, v, S1); S2 = fmaf(e2, v, S2);
      sd1 += e1; sd2 += e2;
    }
  }

  wt1[wv][lane] = S1; wt2[wv][lane] = S2;
  if (lane == 0) { wtd1[wv] = sd1; wtd2[wv] = sd2; }
  __syncthreads();

  float off1 = 0.f, off2 = 0.f, offd1 = 0.f, offd2 = 0.f;
  for (int w2 = 0; w2 < wv; ++w2) {
    off1 += wt1[w2][lane]; off2 += wt2[w2][lane];
    offd1 += wtd1[w2];     offd2 += wtd2[w2];
  }

  float* P1 = ws + WS_P1 + run * (NGRP + 1) * F_OUT;
  float* P2 = ws + WS_P2 + run * (NGRP + 1) * F_OUT;
  float* D1 = ws + WS_D1 + run * (NGRP + 1);
  float* D2 = ws + WS_D2 + run * (NGRP + 1);
  #pragma unroll
  for (int k = 0; k < SBLK; ++k) {
    const int b = wv * SBLK + k;
    P1[b * F_OUT + lane] = off1 + pre1[k];
    P2[b * F_OUT + lane] = off2 + pre2[k];
    if (lane == 0) { D1[b] = offd1 + pd1[k]; D2[b] = offd2 + pd2[k]; }
  }
  if (wv == 15) {      // run totals at b = NGRP
    P1[NGRP * F_OUT + lane] = off1 + S1;
    P2[NGRP * F_OUT + lane] = off2 + S2;
    if (lane == 0) { D1[NGRP] = offd1 + sd1; D2[NGRP] = offd2 + sd2; }
  }
}

// ---------------- K4: per-row 8x binary search + table lookups + residual + ELU ----------
// grid 2048 x 256. One wave per row, lane = output column. Searches are wave-uniform
// (broadcast loads); residual reads are coalesced WhS rows + broadcast E1/E2 scalars.
__global__ __launch_bounds__(256) void k4_out(const float* __restrict__ ws,
                                              float* __restrict__ out) {
  const int t = threadIdx.x, wv = t >> 6, lane = t & 63;
  const int i = blockIdx.x * 4 + wv;
  const float s = ws[WS_ESRC + i];
  const float* DS  = ws + WS_DS;
  const float* E1  = ws + WS_E1;
  const float* E2  = ws + WS_E2;
  const float* WhS = ws + WS_WHS;

  float hi1 = 0.f, lo2 = 0.f, dhi = 0.f, dlo = 0.f;
  #pragma unroll
  for (int r = 0; r < NRUN; ++r) {
    const int rb = r * RUNLEN;
    // first local u with fl(s + d_u) > 0 (exact f32 reference predicate, d ascending)
    int lo = 0, hi = RUNLEN;
    while (lo < hi) {
      int m = (lo + hi) >> 1;
      if (s + DS[rb + m] > 0.0f) hi = m; else lo = m + 1;
    }
    const int tl = lo;                       // in [0, 1024]
    const int b = tl >> 3, rr = tl & 7;
    const int gb = rb + (b << 3);            // global index of group start
    float p1 = ws[WS_P1 + (r * (NGRP + 1) + b) * F_OUT + lane];
    float p2 = ws[WS_P2 + (r * (NGRP + 1) + b) * F_OUT + lane];
    float d1 = ws[WS_D1 + r * (NGRP + 1) + b];
    float d2 = ws[WS_D2 + r * (NGRP + 1) + b];
    for (int o = 0; o < rr; ++o) {           // <=7 residual elements below threshold
      const float e1 = E1[gb + o], e2 = E2[gb + o];
      const float v = WhS[(gb + o) * F_OUT + lane];
      p1 = fmaf(e1, v, p1); p2 = fmaf(e2, v, p2);
      d1 += e1; d2 += e2;
    }
    hi1 += ws[WS_P1 + (r * (NGRP + 1) + NGRP) * F_OUT + lane] - p1;
    lo2 += p2;
    dhi += ws[WS_D1 + r * (NGRP + 1) + NGRP] - d1;
    dlo += d2;
  }

  const float es1 = __expf(s), es2 = __expf(LRELU_ALPHA * s);
  const float num = es1 * hi1 + es2 * lo2;
  const float den = es1 * dhi + es2 * dlo;
  const float rr2 = num / den;
  out[i * F_OUT + lane] = (rr2 > 0.f) ? rr2 : (__expf(rr2) - 1.f);
}

extern "C" void kernel_launch(void* const* d_in, const int* in_sizes, int n_in,
                              void* d_out, int out_size, void* d_ws, size_t ws_size,
                              hipStream_t stream) {
  const float* h = (const float*)d_in[0];
  const float* W = (const float*)d_in[1];
  const float* a = (const float*)d_in[2];
  float* ws = (float*)d_ws;
  float* out = (float*)d_out;

  hipLaunchKernelGGL(k1_wh,         dim3(N_ROWS / 16), dim3(256),  0, stream, h, W, a, ws);
  hipLaunchKernelGGL(k23_sort_scan, dim3(NRUN),        dim3(1024), 0, stream, ws);
  hipLaunchKernelGGL(k4_out,        dim3(N_ROWS / 4),  dim3(256),  0, stream, ws, out);
}

// Round 4
// 103.307 us; speedup vs baseline: 1.5614x; 1.5614x over previous
//
#include <hip/hip_runtime.h>

// GATv1-style single-head attention, N=8192, F_in=128, F_out=64, alpha=0.2.
// exp(leakyrelu(s_i + d_j)) is separable per branch; the branch predicate
// fl(s_i+d_j)>0 is EXACTLY equivalent to mono_enc(d_j) > mono_enc(-s_i).
// Sort j by d (32-block local bitonic + 5 parallel merge rounds), build prefix
// tables of e^d*Wh and e^{0.2d}*Wh sampled every 8 sorted elements (parallel
// group sums + per-column LDS scans), then each output row: 3-stage wave-ballot
// search + table lookup + <=7 coalesced residual terms. O(N^2 F) -> O(N(logN+F)).
// Round-3 lesson: never put a serial phase on <32 blocks (k23 was 64us at 1% occ).

typedef unsigned long long ull;

constexpr int N_ROWS = 8192;
constexpr int F_IN   = 128;
constexpr int F_OUT  = 64;
#define LRELU_ALPHA 0.2f

constexpr int SBLK = 8;                  // prefix-table sampling granularity
constexpr int NGRP = N_ROWS / SBLK;      // 1024 groups; tables hold NGRP+1 entries

// workspace layout in floats (~3.2 MB; ws is far larger)
constexpr int WS_WH   = 0;                          // Wh row-major [j][c]
constexpr int WS_ESRC = WS_WH + N_ROWS * F_OUT;     // e_src[i]
constexpr int WS_KEYA = WS_ESRC + N_ROWS;           // 8192 ull ping
constexpr int WS_KEYB = WS_KEYA + 2 * N_ROWS;       // 8192 ull pong (final sorted)
constexpr int WS_GS1T = WS_KEYB + 2 * N_ROWS;       // group sums TRANSPOSED [c][g]
constexpr int WS_GS2T = WS_GS1T + F_OUT * NGRP;
constexpr int WS_GD1  = WS_GS2T + F_OUT * NGRP;     // NGRP scalars
constexpr int WS_GD2  = WS_GD1 + NGRP;
constexpr int WS_P1   = WS_GD2 + NGRP;              // (NGRP+1) x 64, layout [b][c]
constexpr int WS_P2   = WS_P1 + (NGRP + 1) * F_OUT;
constexpr int WS_D1   = WS_P2 + (NGRP + 1) * F_OUT; // NGRP+1
constexpr int WS_D2   = WS_D1 + (NGRP + 1);
static_assert((WS_KEYA % 2) == 0 && (WS_KEYB % 2) == 0, "keys 8B-aligned");

// monotone float<->uint mapping (ascending uint order == ascending float order)
__device__ __forceinline__ unsigned mono_enc(float f) {
  unsigned u = __float_as_uint(f);
  return u ^ ((u & 0x80000000u) ? 0xFFFFFFFFu : 0x80000000u);
}
__device__ __forceinline__ float mono_dec(unsigned e) {
  unsigned u = e ^ ((e & 0x80000000u) ? 0x80000000u : 0xFFFFFFFFu);
  return __uint_as_float(u);
}

// ---------------- K1: Wh = h @ W ; e_src = Wh@a1 ; keys = (enc(Wh@a2), j) ----------------
__global__ __launch_bounds__(256) void k1_wh(const float* __restrict__ h,
                                             const float* __restrict__ W,
                                             const float* __restrict__ a,
                                             float* __restrict__ ws) {
  __shared__ float hlds[16 * F_IN];
  __shared__ float alds[2 * F_OUT];
  const int t = threadIdx.x;
  const int row0 = blockIdx.x * 16;

  const float4* hsrc = (const float4*)(h + (long)row0 * F_IN);
  float4* hd = (float4*)hlds;
  hd[t]       = hsrc[t];
  hd[t + 256] = hsrc[t + 256];
  if (t < 2 * F_OUT) alds[t] = a[t];
  __syncthreads();

  const int wave = t >> 6, lane = t & 63;
  const float* hp = hlds + (wave * 4) * F_IN;
  float acc0 = 0.f, acc1 = 0.f, acc2 = 0.f, acc3 = 0.f;

  #pragma unroll 4
  for (int k4 = 0; k4 < F_IN; k4 += 4) {
    float4 h0 = *(const float4*)(hp + k4);
    float4 h1 = *(const float4*)(hp + F_IN + k4);
    float4 h2 = *(const float4*)(hp + 2 * F_IN + k4);
    float4 h3 = *(const float4*)(hp + 3 * F_IN + k4);
    float w0 = W[(k4 + 0) * F_OUT + lane];
    float w1 = W[(k4 + 1) * F_OUT + lane];
    float w2 = W[(k4 + 2) * F_OUT + lane];
    float w3 = W[(k4 + 3) * F_OUT + lane];
    acc0 = fmaf(h0.x, w0, acc0); acc0 = fmaf(h0.y, w1, acc0);
    acc0 = fmaf(h0.z, w2, acc0); acc0 = fmaf(h0.w, w3, acc0);
    acc1 = fmaf(h1.x, w0, acc1); acc1 = fmaf(h1.y, w1, acc1);
    acc1 = fmaf(h1.z, w2, acc1); acc1 = fmaf(h1.w, w3, acc1);
    acc2 = fmaf(h2.x, w0, acc2); acc2 = fmaf(h2.y, w1, acc2);
    acc2 = fmaf(h2.z, w2, acc2); acc2 = fmaf(h2.w, w3, acc2);
    acc3 = fmaf(h3.x, w0, acc3); acc3 = fmaf(h3.y, w1, acc3);
    acc3 = fmaf(h3.z, w2, acc3); acc3 = fmaf(h3.w, w3, acc3);
  }

  const int grow = row0 + wave * 4;
  float* Wh = ws + WS_WH;
  Wh[(grow + 0) * F_OUT + lane] = acc0;
  Wh[(grow + 1) * F_OUT + lane] = acc1;
  Wh[(grow + 2) * F_OUT + lane] = acc2;
  Wh[(grow + 3) * F_OUT + lane] = acc3;

  const float a1 = alds[lane], a2 = alds[F_OUT + lane];
  float s0 = acc0 * a1, s1 = acc1 * a1, s2 = acc2 * a1, s3 = acc3 * a1;
  float d0 = acc0 * a2, d1 = acc1 * a2, d2 = acc2 * a2, d3 = acc3 * a2;
  #pragma unroll
  for (int off = 32; off; off >>= 1) {
    s0 += __shfl_down(s0, off); s1 += __shfl_down(s1, off);
    s2 += __shfl_down(s2, off); s3 += __shfl_down(s3, off);
    d0 += __shfl_down(d0, off); d1 += __shfl_down(d1, off);
    d2 += __shfl_down(d2, off); d3 += __shfl_down(d3, off);
  }
  if (lane == 0) {
    ws[WS_ESRC + grow + 0] = s0; ws[WS_ESRC + grow + 1] = s1;
    ws[WS_ESRC + grow + 2] = s2; ws[WS_ESRC + grow + 3] = s3;
    ull* keys = (ull*)(ws + WS_KEYA);
    keys[grow + 0] = ((ull)mono_enc(d0) << 32) | (unsigned)(grow + 0);
    keys[grow + 1] = ((ull)mono_enc(d1) << 32) | (unsigned)(grow + 1);
    keys[grow + 2] = ((ull)mono_enc(d2) << 32) | (unsigned)(grow + 2);
    keys[grow + 3] = ((ull)mono_enc(d3) << 32) | (unsigned)(grow + 3);
  }
}

// ---------------- K2a: 32 blocks, each bitonic-sorts a 256-key chunk in LDS (proven) -----
__global__ __launch_bounds__(256) void k2a_local(ull* __restrict__ keys) {
  __shared__ ull lk[256];
  const int t = threadIdx.x;
  const int base = blockIdx.x * 256;
  lk[t] = keys[base + t];
  __syncthreads();
  for (int k = 2; k <= 256; k <<= 1) {
    for (int j = k >> 1; j > 0; j >>= 1) {
      int p = t ^ j;
      if (p > t) {
        ull x = lk[t], y = lk[p];
        bool asc = ((t & k) == 0);
        if ((x > y) == asc) { lk[t] = y; lk[p] = x; }
      }
      __syncthreads();
    }
  }
  keys[base + t] = lk[t];
}

// ---------------- K2b: parallel merge round, runs of RUN -> 2*RUN (proven) ----------------
template <int RUN>
__global__ __launch_bounds__(256) void k_merge(const ull* __restrict__ src,
                                               ull* __restrict__ dst) {
  const int g = blockIdx.x * 256 + threadIdx.x;
  const ull key = src[g];
  const int pairbase = g & ~(2 * RUN - 1);
  const int local = g - pairbase;
  const bool inA = local < RUN;
  const ull* other = src + pairbase + (inA ? RUN : 0);
  const int idx = inA ? local : (local - RUN);
  int lo = 0, hi = RUN;
  while (lo < hi) {
    int m = (lo + hi) >> 1;
    if (other[m] < key) lo = m + 1; else hi = m;
  }
  dst[pairbase + idx + lo] = key;
}

// ---------------- K3a: per-group partial sums (256 blocks, wave = one group of 8) --------
// Writes group sums TRANSPOSED ([c][g]) so K3b's per-column scans load coalesced.
__global__ __launch_bounds__(256) void k3a_gs(float* __restrict__ ws) {
  const int t = threadIdx.x, wv = t >> 6, lane = t & 63;
  const int g = blockIdx.x * 4 + wv;          // 0..1023
  const ull* K = (const ull*)(ws + WS_KEYB);
  const float* Wh = ws + WS_WH;
  float s1 = 0.f, s2 = 0.f, sd1 = 0.f, sd2 = 0.f;
  #pragma unroll
  for (int o = 0; o < SBLK; ++o) {
    ull key = K[(g << 3) + o];                // wave-uniform broadcast load
    float d = mono_dec((unsigned)(key >> 32));
    int j = (int)(key & 0xFFFFFFFFu);
    float e1 = __expf(d), e2 = __expf(LRELU_ALPHA * d);
    float v = Wh[j * F_OUT + lane];           // coalesced 256B row gather
    s1 = fmaf(e1, v, s1); s2 = fmaf(e2, v, s2);
    sd1 += e1; sd2 += e2;
  }
  ws[WS_GS1T + lane * NGRP + g] = s1;
  ws[WS_GS2T + lane * NGRP + g] = s2;
  if (lane == 0) { ws[WS_GD1 + g] = sd1; ws[WS_GD2 + g] = sd2; }
}

// ---------------- K3b: 130 blocks, per-column LDS scan of 1024 group sums ----------------
// blocks 0..63: GS1T col c -> P1[b][c]; 64..127: GS2T -> P2; 128: GD1->D1; 129: GD2->D2.
__global__ __launch_bounds__(1024) void k3b_scan(float* __restrict__ ws) {
  __shared__ float sm[1024];
  const int t = threadIdx.x;
  const int blk = blockIdx.x;
  const float* src;
  int c = 0;
  if (blk < 64)        { c = blk;      src = ws + WS_GS1T + c * NGRP; }
  else if (blk < 128)  { c = blk - 64; src = ws + WS_GS2T + c * NGRP; }
  else if (blk == 128) { src = ws + WS_GD1; }
  else                 { src = ws + WS_GD2; }

  const float x = src[t];
  sm[t] = x;
  __syncthreads();
  for (int off = 1; off < 1024; off <<= 1) {   // Hillis-Steele inclusive scan
    float y = (t >= off) ? sm[t - off] : 0.f;
    __syncthreads();
    sm[t] += y;
    __syncthreads();
  }
  const float incl = sm[t];
  const float excl = incl - x;
  if (blk < 64) {
    ws[WS_P1 + t * F_OUT + c] = excl;
    if (t == NGRP - 1) ws[WS_P1 + NGRP * F_OUT + c] = incl;
  } else if (blk < 128) {
    ws[WS_P2 + t * F_OUT + c] = excl;
    if (t == NGRP - 1) ws[WS_P2 + NGRP * F_OUT + c] = incl;
  } else if (blk == 128) {
    ws[WS_D1 + t] = excl;
    if (t == NGRP - 1) ws[WS_D1 + NGRP] = incl;
  } else {
    ws[WS_D2 + t] = excl;
    if (t == NGRP - 1) ws[WS_D2 + NGRP] = incl;
  }
}

// ---------------- K4: 3-stage wave-ballot search + table lookup + residual + ELU ---------
// grid 2048 x 256. One wave per row, lane = output column. Search predicate is an
// integer compare on the monotone key encoding (exactly matches fl(s+d)>0).
__global__ __launch_bounds__(256) void k4_out(const float* __restrict__ ws,
                                              float* __restrict__ out) {
  const int t = threadIdx.x, wv = t >> 6, lane = t & 63;
  const int i = blockIdx.x * 4 + wv;
  const ull* K = (const ull*)(ws + WS_KEYB);
  const float s = ws[WS_ESRC + i];
  const float ns = (s == 0.0f) ? 0.0f : -s;   // canonicalize -0
  const unsigned Ki = mono_enc(ns);           // predicate: m > Ki  <=>  fl(s+d) > 0

  // stage 1: 64 samples at stride 128
  unsigned m1 = (unsigned)(K[lane << 7] >> 32);
  ull bal1 = __ballot(m1 <= Ki);
  int tl;
  if (bal1 == 0ull) {
    tl = 0;                                    // even K[0] exceeds Ki
  } else {
    int L1 = 63 - __clzll((long long)bal1);    // last sampled block with key <= Ki
    int base = L1 << 7;
    // stage 2: 64 samples at stride 2 inside the 128-block (lane0 sample <= Ki)
    unsigned m2 = (unsigned)(K[base + (lane << 1)] >> 32);
    ull bal2 = __ballot(m2 <= Ki);
    int L2 = 63 - __clzll((long long)bal2);
    int p = base + (L2 << 1) + 1;
    // stage 3: single probe resolves the pair
    unsigned m3 = (unsigned)(K[p] >> 32);
    tl = p + ((m3 <= Ki) ? 1 : 0);
  }
  const int b = tl >> 3, rr = tl & 7;

  float p1 = ws[WS_P1 + b * F_OUT + lane];
  float p2 = ws[WS_P2 + b * F_OUT + lane];
  float d1 = ws[WS_D1 + b], d2 = ws[WS_D2 + b];
  const float p1tot = ws[WS_P1 + NGRP * F_OUT + lane];
  const float d1tot = ws[WS_D1 + NGRP];
  const float* Wh = ws + WS_WH;

  for (int o = 0; o < rr; ++o) {               // <=7 residual elements below threshold
    ull key = K[(b << 3) + o];
    float d = mono_dec((unsigned)(key >> 32));
    int j = (int)(key & 0xFFFFFFFFu);
    float e1 = __expf(d), e2 = __expf(LRELU_ALPHA * d);
    float v = Wh[j * F_OUT + lane];            // coalesced 256B row
    p1 = fmaf(e1, v, p1); p2 = fmaf(e2, v, p2);
    d1 += e1; d2 += e2;
  }

  const float es1 = __expf(s), es2 = __expf(LRELU_ALPHA * s);
  const float num = es1 * (p1tot - p1) + es2 * p2;
  const float den = es1 * (d1tot - d1) + es2 * d2;
  const float r = num / den;
  out[i * F_OUT + lane] = (r > 0.f) ? r : (__expf(r) - 1.f);
}

extern "C" void kernel_launch(void* const* d_in, const int* in_sizes, int n_in,
                              void* d_out, int out_size, void* d_ws, size_t ws_size,
                              hipStream_t stream) {
  const float* h = (const float*)d_in[0];
  const float* W = (const float*)d_in[1];
  const float* a = (const float*)d_in[2];
  float* ws = (float*)d_ws;
  float* out = (float*)d_out;
  ull* keyA = (ull*)(ws + WS_KEYA);
  ull* keyB = (ull*)(ws + WS_KEYB);

  hipLaunchKernelGGL(k1_wh,         dim3(N_ROWS / 16), dim3(256),  0, stream, h, W, a, ws);
  hipLaunchKernelGGL(k2a_local,     dim3(32),          dim3(256),  0, stream, keyA);
  hipLaunchKernelGGL(k_merge<256>,  dim3(32),          dim3(256),  0, stream, keyA, keyB);
  hipLaunchKernelGGL(k_merge<512>,  dim3(32),          dim3(256),  0, stream, keyB, keyA);
  hipLaunchKernelGGL(k_merge<1024>, dim3(32),          dim3(256),  0, stream, keyA, keyB);
  hipLaunchKernelGGL(k_merge<2048>, dim3(32),          dim3(256),  0, stream, keyB, keyA);
  hipLaunchKernelGGL(k_merge<4096>, dim3(32),          dim3(256),  0, stream, keyA, keyB);
  hipLaunchKernelGGL(k3a_gs,        dim3(NGRP / 4),    dim3(256),  0, stream, ws);
  hipLaunchKernelGGL(k3b_scan,      dim3(130),         dim3(1024), 0, stream, ws);
  hipLaunchKernelGGL(k4_out,        dim3(N_ROWS / 4),  dim3(256),  0, stream, ws, out);
}

// Round 9
// 101.481 us; speedup vs baseline: 1.5895x; 1.0180x over previous
//
#include <hip/hip_runtime.h>

// GATv1-style single-head attention, N=8192, F_in=128, F_out=64, alpha=0.2.
// exp(leakyrelu(s_i + d_j)) is separable per branch; predicate fl(s+d)>0 is
// exactly mono_enc(d) > mono_enc(-s). Sort j by d, prefix tables of e^d*Wh and
// e^{0.2d}*Wh sampled every 8 sorted elements, per-row ballot search + <=7
// residual terms. O(N^2 F) -> O(N(logN+F)).
// HARD CONSTRAINTS (learned r5-r8):
//   - hipLaunchCooperativeKernel aborts harness graph capture (r5).
//   - hipMemsetAsync inside kernel_launch is suspect (r6).
//   - software grid barriers deadlock -> HSA abort (r7). No grid-wide sync.
//   - r8 (plain dispatches, clean audit) also aborted => environment likely
//     wedged by r7's deadlock; this round uses ONLY hardware-proven kernel
//     bodies to re-establish ground truth.
// Pipeline (8 dispatches, all components previously passed on HW):
//   k1_wh (r2/r4) -> k2a_1024 (r3's proven 1024-elem LDS bitonic, 8 blocks)
//   -> k_merge<1024/2048/4096> (r2/r4 proven template) -> k3a_gs + k3b_scan
//   (r4 proven) -> k4_out (r4 proven ballot search).

typedef unsigned long long ull;

constexpr int N_ROWS = 8192;
constexpr int F_IN   = 128;
constexpr int F_OUT  = 64;
#define LRELU_ALPHA 0.2f

constexpr int SBLK = 8;                  // prefix-table sampling granularity
constexpr int NGRP = N_ROWS / SBLK;      // 1024 groups; tables hold NGRP+1 entries

// workspace layout in floats (~3.2 MB; ws is 256 MiB)
constexpr int WS_WH   = 0;                          // Wh row-major [j][c]
constexpr int WS_ESRC = WS_WH + N_ROWS * F_OUT;     // e_src[i]
constexpr int WS_KEYA = WS_ESRC + N_ROWS;           // 8192 ull ping
constexpr int WS_KEYB = WS_KEYA + 2 * N_ROWS;       // 8192 ull pong (final sorted)
constexpr int WS_GS1T = WS_KEYB + 2 * N_ROWS;       // group sums TRANSPOSED [c][g]
constexpr int WS_GS2T = WS_GS1T + F_OUT * NGRP;
constexpr int WS_GD1  = WS_GS2T + F_OUT * NGRP;     // NGRP scalars
constexpr int WS_GD2  = WS_GD1 + NGRP;
constexpr int WS_P1   = WS_GD2 + NGRP;              // (NGRP+1) x 64, layout [b][c]
constexpr int WS_P2   = WS_P1 + (NGRP + 1) * F_OUT;
constexpr int WS_D1   = WS_P2 + (NGRP + 1) * F_OUT; // NGRP+1
constexpr int WS_D2   = WS_D1 + (NGRP + 1);
static_assert((WS_KEYA % 2) == 0 && (WS_KEYB % 2) == 0, "keys 8B-aligned");

// monotone float<->uint mapping (ascending uint order == ascending float order)
__device__ __forceinline__ unsigned mono_enc(float f) {
  unsigned u = __float_as_uint(f);
  return u ^ ((u & 0x80000000u) ? 0xFFFFFFFFu : 0x80000000u);
}
__device__ __forceinline__ float mono_dec(unsigned e) {
  unsigned u = e ^ ((e & 0x80000000u) ? 0x80000000u : 0xFFFFFFFFu);
  return __uint_as_float(u);
}

// ---------------- K1: Wh = h @ W ; e_src = Wh@a1 ; keys = (enc(Wh@a2), j) ----------------
// grid 512 x 256 threads. 16 rows/block, wave handles 4 rows, lane = output col. (proven)
__global__ __launch_bounds__(256) void k1_wh(const float* __restrict__ h,
                                             const float* __restrict__ W,
                                             const float* __restrict__ a,
                                             float* __restrict__ ws) {
  __shared__ float hlds[16 * F_IN];
  __shared__ float alds[2 * F_OUT];
  const int t = threadIdx.x;
  const int row0 = blockIdx.x * 16;

  const float4* hsrc = (const float4*)(h + (long)row0 * F_IN);
  float4* hd = (float4*)hlds;
  hd[t]       = hsrc[t];
  hd[t + 256] = hsrc[t + 256];
  if (t < 2 * F_OUT) alds[t] = a[t];
  __syncthreads();

  const int wave = t >> 6, lane = t & 63;
  const float* hp = hlds + (wave * 4) * F_IN;
  float acc0 = 0.f, acc1 = 0.f, acc2 = 0.f, acc3 = 0.f;

  #pragma unroll 4
  for (int k4 = 0; k4 < F_IN; k4 += 4) {
    float4 h0 = *(const float4*)(hp + k4);
    float4 h1 = *(const float4*)(hp + F_IN + k4);
    float4 h2 = *(const float4*)(hp + 2 * F_IN + k4);
    float4 h3 = *(const float4*)(hp + 3 * F_IN + k4);
    float w0 = W[(k4 + 0) * F_OUT + lane];
    float w1 = W[(k4 + 1) * F_OUT + lane];
    float w2 = W[(k4 + 2) * F_OUT + lane];
    float w3 = W[(k4 + 3) * F_OUT + lane];
    acc0 = fmaf(h0.x, w0, acc0); acc0 = fmaf(h0.y, w1, acc0);
    acc0 = fmaf(h0.z, w2, acc0); acc0 = fmaf(h0.w, w3, acc0);
    acc1 = fmaf(h1.x, w0, acc1); acc1 = fmaf(h1.y, w1, acc1);
    acc1 = fmaf(h1.z, w2, acc1); acc1 = fmaf(h1.w, w3, acc1);
    acc2 = fmaf(h2.x, w0, acc2); acc2 = fmaf(h2.y, w1, acc2);
    acc2 = fmaf(h2.z, w2, acc2); acc2 = fmaf(h2.w, w3, acc2);
    acc3 = fmaf(h3.x, w0, acc3); acc3 = fmaf(h3.y, w1, acc3);
    acc3 = fmaf(h3.z, w2, acc3); acc3 = fmaf(h3.w, w3, acc3);
  }

  const int grow = row0 + wave * 4;
  float* Wh = ws + WS_WH;
  Wh[(grow + 0) * F_OUT + lane] = acc0;
  Wh[(grow + 1) * F_OUT + lane] = acc1;
  Wh[(grow + 2) * F_OUT + lane] = acc2;
  Wh[(grow + 3) * F_OUT + lane] = acc3;

  const float a1 = alds[lane], a2 = alds[F_OUT + lane];
  float s0 = acc0 * a1, s1 = acc1 * a1, s2 = acc2 * a1, s3 = acc3 * a1;
  float d0 = acc0 * a2, d1 = acc1 * a2, d2 = acc2 * a2, d3 = acc3 * a2;
  #pragma unroll
  for (int off = 32; off; off >>= 1) {
    s0 += __shfl_down(s0, off); s1 += __shfl_down(s1, off);
    s2 += __shfl_down(s2, off); s3 += __shfl_down(s3, off);
    d0 += __shfl_down(d0, off); d1 += __shfl_down(d1, off);
    d2 += __shfl_down(d2, off); d3 += __shfl_down(d3, off);
  }
  if (lane == 0) {
    ws[WS_ESRC + grow + 0] = s0; ws[WS_ESRC + grow + 1] = s1;
    ws[WS_ESRC + grow + 2] = s2; ws[WS_ESRC + grow + 3] = s3;
    ull* keys = (ull*)(ws + WS_KEYA);
    keys[grow + 0] = ((ull)mono_enc(d0) << 32) | (unsigned)(grow + 0);
    keys[grow + 1] = ((ull)mono_enc(d1) << 32) | (unsigned)(grow + 1);
    keys[grow + 2] = ((ull)mono_enc(d2) << 32) | (unsigned)(grow + 2);
    keys[grow + 3] = ((ull)mono_enc(d3) << 32) | (unsigned)(grow + 3);
  }
}

// ---------------- K2: 8 blocks x 1024 threads, bitonic-sort 1024-key runs in LDS ---------
// Exact sort loop from round-3's k23_sort_scan (hardware-proven correct).
__global__ __launch_bounds__(1024) void k2a_1024(ull* __restrict__ keys) {
  __shared__ ull lk[1024];          // 8 KB
  const int t = threadIdx.x;
  const int base = blockIdx.x * 1024;
  lk[t] = keys[base + t];
  __syncthreads();
  for (int k = 2; k <= 1024; k <<= 1) {
    for (int j = k >> 1; j > 0; j >>= 1) {
      int p = t ^ j;
      if (p > t) {
        ull x = lk[t], y = lk[p];
        bool asc = ((t & k) == 0);
        if ((x > y) == asc) { lk[t] = y; lk[p] = x; }
      }
      __syncthreads();
    }
  }
  keys[base + t] = lk[t];
}

// ---------------- K2b: parallel merge round, runs of RUN -> 2*RUN (proven) ----------------
// Keys are unique (low 32 bits = j), so pos = own_index + count(other_run < key).
template <int RUN>
__global__ __launch_bounds__(256) void k_merge(const ull* __restrict__ src,
                                               ull* __restrict__ dst) {
  const int g = blockIdx.x * 256 + threadIdx.x;
  const ull key = src[g];
  const int pairbase = g & ~(2 * RUN - 1);
  const int local = g - pairbase;
  const bool inA = local < RUN;
  const ull* other = src + pairbase + (inA ? RUN : 0);
  const int idx = inA ? local : (local - RUN);
  int lo = 0, hi = RUN;
  while (lo < hi) {
    int m = (lo + hi) >> 1;
    if (other[m] < key) lo = m + 1; else hi = m;
  }
  dst[pairbase + idx + lo] = key;
}

// ---------------- K3a: per-group partial sums (256 blocks, wave = one group of 8) --------
// Writes group sums TRANSPOSED ([c][g]) so K3b's per-column scans load coalesced. (proven)
__global__ __launch_bounds__(256) void k3a_gs(float* __restrict__ ws) {
  const int t = threadIdx.x, wv = t >> 6, lane = t & 63;
  const int g = blockIdx.x * 4 + wv;          // 0..1023
  const ull* K = (const ull*)(ws + WS_KEYB);
  const float* Wh = ws + WS_WH;
  float s1 = 0.f, s2 = 0.f, sd1 = 0.f, sd2 = 0.f;
  #pragma unroll
  for (int o = 0; o < SBLK; ++o) {
    ull key = K[(g << 3) + o];                // wave-uniform broadcast load
    float d = mono_dec((unsigned)(key >> 32));
    int j = (int)(key & 0xFFFFFFFFu);
    float e1 = __expf(d), e2 = __expf(LRELU_ALPHA * d);
    float v = Wh[j * F_OUT + lane];           // coalesced 256B row gather
    s1 = fmaf(e1, v, s1); s2 = fmaf(e2, v, s2);
    sd1 += e1; sd2 += e2;
  }
  ws[WS_GS1T + lane * NGRP + g] = s1;
  ws[WS_GS2T + lane * NGRP + g] = s2;
  if (lane == 0) { ws[WS_GD1 + g] = sd1; ws[WS_GD2 + g] = sd2; }
}

// ---------------- K3b: 130 blocks, per-column LDS scan of 1024 group sums (proven) -------
// blocks 0..63: GS1T col c -> P1[b][c]; 64..127: GS2T -> P2; 128: GD1->D1; 129: GD2->D2.
__global__ __launch_bounds__(1024) void k3b_scan(float* __restrict__ ws) {
  __shared__ float sm[1024];
  const int t = threadIdx.x;
  const int blk = blockIdx.x;
  const float* src;
  int c = 0;
  if (blk < 64)        { c = blk;      src = ws + WS_GS1T + c * NGRP; }
  else if (blk < 128)  { c = blk - 64; src = ws + WS_GS2T + c * NGRP; }
  else if (blk == 128) { src = ws + WS_GD1; }
  else                 { src = ws + WS_GD2; }

  const float x = src[t];
  sm[t] = x;
  __syncthreads();
  for (int off = 1; off < 1024; off <<= 1) {   // Hillis-Steele inclusive scan
    float y = (t >= off) ? sm[t - off] : 0.f;
    __syncthreads();
    sm[t] += y;
    __syncthreads();
  }
  const float incl = sm[t];
  const float excl = incl - x;
  if (blk < 64) {
    ws[WS_P1 + t * F_OUT + c] = excl;
    if (t == NGRP - 1) ws[WS_P1 + NGRP * F_OUT + c] = incl;
  } else if (blk < 128) {
    ws[WS_P2 + t * F_OUT + c] = excl;
    if (t == NGRP - 1) ws[WS_P2 + NGRP * F_OUT + c] = incl;
  } else if (blk == 128) {
    ws[WS_D1 + t] = excl;
    if (t == NGRP - 1) ws[WS_D1 + NGRP] = incl;
  } else {
    ws[WS_D2 + t] = excl;
    if (t == NGRP - 1) ws[WS_D2 + NGRP] = incl;
  }
}

// ---------------- K4: 3-stage wave-ballot search + table lookup + residual + ELU ---------
// grid 2048 x 256. One wave per row, lane = output column. (proven)
__global__ __launch_bounds__(256) void k4_out(const float* __restrict__ ws,
                                              float* __restrict__ out) {
  const int t = threadIdx.x, wv = t >> 6, lane = t & 63;
  const int i = blockIdx.x * 4 + wv;
  const ull* K = (const ull*)(ws + WS_KEYB);
  const float s = ws[WS_ESRC + i];
  const float ns = (s == 0.0f) ? 0.0f : -s;   // canonicalize -0
  const unsigned Ki = mono_enc(ns);           // m > Ki  <=>  fl(s+d) > 0

  unsigned m1 = (unsigned)(K[lane << 7] >> 32);
  ull bal1 = __ballot(m1 <= Ki);
  int tl;
  if (bal1 == 0ull) {
    tl = 0;
  } else {
    int L1 = 63 - __clzll((long long)bal1);
    int base = L1 << 7;
    unsigned m2 = (unsigned)(K[base + (lane << 1)] >> 32);
    ull bal2 = __ballot(m2 <= Ki);
    int L2 = 63 - __clzll((long long)bal2);
    int p = base + (L2 << 1) + 1;
    unsigned m3 = (unsigned)(K[p] >> 32);
    tl = p + ((m3 <= Ki) ? 1 : 0);
  }
  const int b = tl >> 3, rr = tl & 7;

  float p1 = ws[WS_P1 + b * F_OUT + lane];
  float p2 = ws[WS_P2 + b * F_OUT + lane];
  float d1 = ws[WS_D1 + b], d2 = ws[WS_D2 + b];
  const float p1tot = ws[WS_P1 + NGRP * F_OUT + lane];
  const float d1tot = ws[WS_D1 + NGRP];
  const float* Wh = ws + WS_WH;

  for (int o = 0; o < rr; ++o) {               // <=7 residual elements
    ull key = K[(b << 3) + o];
    float d = mono_dec((unsigned)(key >> 32));
    int j = (int)(key & 0xFFFFFFFFu);
    float e1 = __expf(d), e2 = __expf(LRELU_ALPHA * d);
    float v = Wh[j * F_OUT + lane];            // coalesced 256B row
    p1 = fmaf(e1, v, p1); p2 = fmaf(e2, v, p2);
    d1 += e1; d2 += e2;
  }

  const float es1 = __expf(s), es2 = __expf(LRELU_ALPHA * s);
  const float num = es1 * (p1tot - p1) + es2 * p2;
  const float den = es1 * (d1tot - d1) + es2 * d2;
  const float r = num / den;
  out[i * F_OUT + lane] = (r > 0.f) ? r : (__expf(r) - 1.f);
}

extern "C" void kernel_launch(void* const* d_in, const int* in_sizes, int n_in,
                              void* d_out, int out_size, void* d_ws, size_t ws_size,
                              hipStream_t stream) {
  const float* h = (const float*)d_in[0];
  const float* W = (const float*)d_in[1];
  const float* a = (const float*)d_in[2];
  float* ws = (float*)d_ws;
  float* out = (float*)d_out;
  ull* keyA = (ull*)(ws + WS_KEYA);
  ull* keyB = (ull*)(ws + WS_KEYB);

  hipLaunchKernelGGL(k1_wh,         dim3(N_ROWS / 16), dim3(256),  0, stream, h, W, a, ws);
  hipLaunchKernelGGL(k2a_1024,      dim3(8),           dim3(1024), 0, stream, keyA);
  hipLaunchKernelGGL(k_merge<1024>, dim3(32),          dim3(256),  0, stream, keyA, keyB);
  hipLaunchKernelGGL(k_merge<2048>, dim3(32),          dim3(256),  0, stream, keyB, keyA);
  hipLaunchKernelGGL(k_merge<4096>, dim3(32),          dim3(256),  0, stream, keyA, keyB);
  hipLaunchKernelGGL(k3a_gs,        dim3(NGRP / 4),    dim3(256),  0, stream, ws);
  hipLaunchKernelGGL(k3b_scan,      dim3(130),         dim3(1024), 0, stream, ws);
  hipLaunchKernelGGL(k4_out,        dim3(N_ROWS / 4),  dim3(256),  0, stream, ws, out);
}